// Round 14
// baseline (405.746 us; speedup 1.0000x reference)
//
#include <hip/hip_runtime.h>
#include <hip/hip_bf16.h>
#include <math.h>

// ---------------------------------------------------------------------------
// DeepDCNN: emb-gather -> 4x [grouped full-conv + pair-fold + ordered top-k +
// tanh] -> FC.  All fp32.
//
// R14 = R13 (309.7us best, absmax 0.0) + hybrid-count selects in layer12
// ONLY (4th and final attempt at the SALU->VALU count move):
//  - wave_select1_hyb: per-round count = per-lane VALU adds (<=5 bits) +
//    5-ballot binary sum.  SALU/round ~37 -> ~15; VALU 17 -> ~40.  At 10-14
//    select-waves/CU the ballot path is SALU-throughput-bound on the CU's
//    ONE scalar unit (~370-520 cyc/round); hybrid rebalances to ~150.
//  - regalloc-cliff mitigations vs R9's failed attempt: (a) hybrid is a
//    SEPARATE function used only by layer12 -- conv template keeps ballot,
//    so conv instantiations can't perturb layer12's allocation; (b) acc
//    bias-init DEFERRED past the ph0 select (13 regs of pure bias constants
//    were live through the worst-pressure point; now dead there).
// GATES: VGPR<=64, WRITE~28.7MB, FETCH~8.6MB, absmax 0.0.  Spill => the
// VALU-count line is permanently closed; revert to R13.
//
// CLOSED: DPP counting (R8 spill), shared-template hybrid (R9 spill),
// launch_bounds(896,7) (R10 36-VGPR misalloc), LDS-histogram radix (R11
// bank-conflict skew + drift), layer12 LDS-occupancy (R12 null), L3
// LDS-occupancy (R13 ~null).  R1-R7: only removed instructions / traffic /
// residency move the clean total; pipe-shuffles are neutral.
// ---------------------------------------------------------------------------

#if defined(__has_builtin)
#if __has_builtin(__builtin_amdgcn_ballot_w64)
#define BALLOT64(expr) __builtin_amdgcn_ballot_w64(expr)
#endif
#endif
#ifndef BALLOT64
#define BALLOT64(expr) __ballot(expr)
#endif

__device__ __forceinline__ unsigned f2ord(float f) {
    unsigned u = __float_as_uint(f);
    return (u & 0x80000000u) ? ~u : (u | 0x80000000u);
}
__device__ __forceinline__ float ord2f(unsigned key) {
    unsigned u = (key & 0x80000000u) ? (key & 0x7fffffffu) : ~key;
    return __uint_as_float(u);
}
// tanh via exp + hw rcp: 1 - 2*rcp(e^{2x}+1).  |err| ~1e-7.  Keys are
// pre-tanh so selection ordering is unaffected.
__device__ __forceinline__ float tanh_fast(float x) {
    float e = __expf(2.f * x);
    return 1.f - 2.f * __builtin_amdgcn_rcpf(e + 1.f);
}
__device__ __forceinline__ int mbcnt64(unsigned long long m) {
    return __builtin_amdgcn_mbcnt_hi((unsigned)(m >> 32),
           __builtin_amdgcn_mbcnt_lo((unsigned)m, 0u));
}

// ---- compaction + tanh -> stage (LDS) [-> optional coalesced copy-out] ----
// T = threshold key; stable (earliest ties kept), order-preserving.
// COPY=false: kept values land scattered-compacted in stage and stay there
// (used by the fused kernel, stage = conv-input row in LDS).
// COPY=true: float4 copy stage -> out (k multiple of 4; 16B-aligned rows).
template<int CH, bool COPY>
__device__ __forceinline__ void select_finish(const unsigned* keys, unsigned T,
                                              int k, float* stage,
                                              float* __restrict__ out)
{
    int g = 0, e = 0;
    #pragma unroll
    for (int i = 0; i < CH; ++i) { g += (keys[i] > T); e += (keys[i] == T); }

    int gtBefore = 0, eqBefore = 0, totG = 0;
    #pragma unroll
    for (int b = 0; b < 5; ++b) {     // CH <= 17 < 32 -> 5 bits
        unsigned long long mg = BALLOT64((((g >> b) & 1) != 0));
        unsigned long long me = BALLOT64((((e >> b) & 1) != 0));
        gtBefore += mbcnt64(mg) << b;
        eqBefore += mbcnt64(me) << b;
        totG     += __popcll(mg) << b;
    }
    const int needTies = k - totG;    // # of ==T to keep (earliest)

    int gRun = 0, eRun = 0;
    #pragma unroll
    for (int i = 0; i < CH; ++i) {
        const unsigned key = keys[i];
        const bool isG = key > T;
        const bool isE = key == T;
        const int eIdx = eqBefore + eRun;
        const int dst = gtBefore + gRun + min(eIdx, needTies);
        if (isG || (isE && eIdx < needTies))
            stage[dst] = tanh_fast(ord2f(key));
        gRun += isG; eRun += isE;
    }
    if (COPY) {
        // coalesced vectorized copy-out (same-wave DS ordering makes the
        // scatter-write -> contiguous-read sequence safe without barriers)
        const int lane = threadIdx.x & 63;
        const float4* s4 = (const float4*)stage;
        float4* o4 = (float4*)out;
        #pragma unroll 1
        for (int i = lane; i < (k >> 2); i += 64)
            o4[i] = s4[i];
    }
}

// ---- single-row exact top-k, HYBRID counting (layer12 ONLY) --------------
// Per-lane VALU partial count (<=5 bits) + 5-ballot binary sum: ~15 SALU +
// ~40 VALU per round vs ballot's ~37 SALU + 17 VALU.  Selects run with
// 10-14 waves/CU sharing ONE scalar unit -> ballot rounds are SALU-bound.
template<int CH, bool COPY>
__device__ void wave_select1_hyb(const unsigned* keys, int k, float* stage,
                                 float* __restrict__ out)
{
    unsigned p = 0u;
    int above = 0, buck = 64 * CH;
    #pragma unroll 1
    for (int pos = 31; pos >= 0; --pos) {
        const unsigned t = p | (1u << pos);
        int cnt = 0;
        #pragma unroll
        for (int i = 0; i < CH; ++i)
            cnt += (keys[i] >= t);
        int c = 0;
        #pragma unroll
        for (int b2 = 0; b2 < 5; ++b2) {
            unsigned long long m = BALLOT64((((cnt >> b2) & 1) != 0));
            c += __popcll(m) << b2;
        }
        const int inb = c - above;        // bucket members with bit=1
        const int rem = k - above;
        if (inb >= rem) { p = t; buck = inb; }
        else            { above += inb; buck -= inb; }
        if (buck == k - above) break;
    }
    select_finish<CH, COPY>(keys, p, k, stage, out);
}

// ---- N-row exact top-k, interleaved BALLOT chains (conv L3/L4 only) ------
template<int N, int CH>
__device__ void wave_selectN_ballot(const unsigned (*keys)[CH], int k,
                                    float* stage, float* const* outs)
{
    unsigned p[N];
    int above[N], buck[N];
    #pragma unroll
    for (int n = 0; n < N; ++n) { p[n] = 0u; above[n] = 0; buck[n] = 64 * CH; }

    unsigned doneMask = 0;
    const unsigned allDone = (1u << N) - 1u;
    #pragma unroll 1
    for (int pos = 31; pos >= 0; --pos) {
        #pragma unroll
        for (int n = 0; n < N; ++n) {
            if (!((doneMask >> n) & 1u)) {        // wave-uniform branch
                const unsigned t = p[n] | (1u << pos);
                int c = 0;
                #pragma unroll
                for (int i = 0; i < CH; ++i)
                    c += __popcll(BALLOT64((keys[n][i] >= t)));
                const int inb = c - above[n];
                const int rem = k - above[n];
                if (inb >= rem) { p[n] = t; buck[n] = inb; }
                else            { above[n] += inb; buck[n] -= inb; }
                if (buck[n] == k - above[n]) doneMask |= (1u << n);
            }
        }
        if (doneMask == allDone) break;
    }
    #pragma unroll
    for (int n = 0; n < N; ++n)
        select_finish<CH, true>(keys[n], p[n], k, stage, outs[n]);
}

// ---------------------------------------------------------------------------
// Fused layers 1+2.  grid (16, 64) -> XCD-swizzled to (j2, b), block 896 =
// 14 waves.
// Per block:
//   phase ph=0/1 (L1 group g = 2*j2+ph):
//     - waves 0..9: L1 conv row f1=wav, top-768 HYBRID select + tanh
//       directly into z1[wav][4..772)
//     - all 14 waves: L2 partial conv, filter f=wav, input half h=ph
//       (acc bias-init deferred to the ph==0 restage block -> 13 fewer
//        live regs through the ph0 select)
//     - xr restage for ph=1 overlaps the ph=0 accumulation
//   epilogue: barrier (z1 dead), top-512 HYBRID select per filter staged
//   into z1 -> float4 write to Z2.
// LDS: z1 10x836x4 = 33.4 KB + uni(xr[2][1100]) 8.8 KB = 41.3 KB.
// XCD swizzle: all 16 j2-blocks of batch b land on xcd = b>>3 (R6:
// FETCH 56->8.6MB; per-XCD emb working set 2MB < 4MB L2).
// ---------------------------------------------------------------------------
__global__ __launch_bounds__(896) void layer12_fused(
    const int* __restrict__ tokens, const float* __restrict__ emb,
    const float* __restrict__ W1, const float* __restrict__ B1,
    const float* __restrict__ W2, const float* __restrict__ B2,
    float* __restrict__ Z2)
{
    // XCD-aware remap (bijective: 1024 = 8 xcd * 128)
    const int lin = blockIdx.x + (blockIdx.y << 4);
    const int xcd = lin & 7;
    const int q   = lin >> 3;           // 0..127
    const int j2  = q >> 3;             // 0..15
    const int b   = (xcd << 3) + (q & 7); // 0..63; all j2 of b on one xcd

    const int t  = threadIdx.x;
    const int wav  = t >> 6;            // 0..13
    const int lane = t & 63;

    __shared__ __align__(16) float z1[10][836];
    __shared__ __align__(16) float uni[2 * 1100];   // xr[2][1100]
    float (*xr)[1100] = reinterpret_cast<float (*)[1100]>(uni);
    const float2* emb2 = (const float2*)emb;

    // zero ONLY the pad words: [0,4) and [772,836) per row (68 words x 10
    // rows).  The value region [4,772) is fully overwritten by each phase's
    // select before any read.
    for (int i = t; i < 680; i += 896) {
        const int r = i / 68;
        const int w = i - r * 68;
        z1[r][(w < 4) ? w : (768 + w)] = 0.f;
    }

    const int f = __builtin_amdgcn_readfirstlane(wav);
    float acc[13];                      // bias-init DEFERRED (see ph==0 block)
    const int base = lane * 13;

    // stage xr for phase 0 (L1 group g = 2*j2; emb dim pair g)
    {
        const int g = 2 * j2;
        for (int i = t; i < 1100; i += 896) {
            int s = i - 6; float a = 0.f, c = 0.f;
            if (s >= 0 && s < 1024) {
                int tok = tokens[b * 1024 + s];
                float2 v = emb2[(size_t)tok * 32 + g];
                a = v.x; c = v.y;
            }
            xr[0][i] = a; xr[1][i] = c;
        }
    }
    __syncthreads();   // xr(0) + z1 pad zeros visible

    #pragma unroll 1
    for (int ph = 0; ph < 2; ++ph) {
        const int g = 2 * j2 + ph;

        // ---- L1: conv + hybrid select + tanh -> z1 row (waves 0..9) ----
        if (wav < 10) {
            const int f1 = wav;
            float wa[7], wb[7];
            #pragma unroll
            for (int k2 = 0; k2 < 7; ++k2) {
                wa[k2] = W1[(2 * g * 10 + f1) * 7 + k2];
                wb[k2] = W1[((2 * g + 1) * 10 + f1) * 7 + k2];
            }
            const float bias1 = B1[2 * g * 10 + f1] + B1[(2 * g + 1) * 10 + f1];
            const int beg = lane * 17;
            unsigned keys1[17];
            #pragma unroll
            for (int i = 0; i < 17; ++i) {
                float a1 = bias1;
                #pragma unroll
                for (int k2 = 0; k2 < 7; ++k2)
                    a1 += xr[0][beg + i + k2] * wa[k2]
                        + xr[1][beg + i + k2] * wb[k2];
                keys1[i] = (beg + i < 1030) ? f2ord(a1) : 0u;
            }
            wave_select1_hyb<17, false>(keys1, 768, &z1[wav][4], nullptr);
        }
        __syncthreads();   // z1(ph) ready; all xr reads of this phase done

        if (ph == 0) {
            // restage xr for phase 1 — overlaps the h=0 accumulation below
            const int g1 = 2 * j2 + 1;
            for (int i = t; i < 1100; i += 896) {
                int s = i - 6; float a = 0.f, c = 0.f;
                if (s >= 0 && s < 1024) {
                    int tok = tokens[b * 1024 + s];
                    float2 v = emb2[(size_t)tok * 32 + g1];
                    a = v.x; c = v.y;
                }
                xr[0][i] = a; xr[1][i] = c;
            }
            // deferred acc bias-init (freed 13 regs through the ph0 select)
            const float bias = B2[(2 * j2) * 14 + f]
                             + B2[(2 * j2 + 1) * 14 + f];
            #pragma unroll
            for (int i = 0; i < 13; ++i) acc[i] = bias;
        }

        // ---- L2 partial conv: all 14 waves, filter f, half h=ph ----
        {
            const float* Wp0 = W2 + (size_t)((2 * j2 + ph) * 14 + f) * 10 * 5;
            #pragma unroll 1
            for (int r = 0; r < 10; ++r) {
                float win[17];
                #pragma unroll
                for (int p = 0; p < 17; ++p) win[p] = z1[r][base + p];
                const float* Wp = Wp0 + r * 5;
                #pragma unroll
                for (int k2 = 0; k2 < 5; ++k2) {
                    const float w0 = Wp[k2];
                    #pragma unroll
                    for (int i = 0; i < 13; ++i)
                        acc[i] = fmaf(win[i + k2], w0, acc[i]);
                }
            }
        }
        if (ph == 0) __syncthreads();  // xr(1) staged & z1(0) fully consumed
    }

    // ---- L2 select: hybrid, k=512, staged into DEAD z1 ----
    // Barrier: every wave must finish its h=1 conv reads of z1 before any
    // wave overwrites z1 with its stage data.
    __syncthreads();
    unsigned keys2[13];
    #pragma unroll
    for (int i = 0; i < 13; ++i)
        keys2[i] = (base + i < 772) ? f2ord(acc[i]) : 0u;
    float* stage = ((float*)z1) + wav * 512;   // 14*512 = 7168 <= 8360 words
    float* outp = Z2 + ((size_t)b * 224 + (size_t)j2 * 14 + f) * 512;
    wave_select1_hyb<13, true>(keys2, 512, stage, outp);
}

// ---------------------------------------------------------------------------
// Fused conv + fold + select + tanh (layers 3-4).  Unchanged from R13:
// XCD-swizzled grid; selects stage into xs (dead after conv; barrier).
// L3 LDS 16.3KB (4-phase), L4 46.4KB (1-phase).  Ballot selects.
// ---------------------------------------------------------------------------
template <int IPG, int NF, int K, int SIN, int SOUT, int KSEL, int NW, int CH,
          int PHASES, int GRIDJ>
__global__ __launch_bounds__(NW * 64) void conv_fold_select_kernel(
    const float* __restrict__ X, const float* __restrict__ W,
    const float* __restrict__ Bias, float* __restrict__ Z,
    int Cin, int Cfold)
{
    static_assert(NF == 2 * NW, "2 filters per wave");
    static_assert(64 * CH >= SOUT, "chunk covers row");
    constexpr int W2 = 64 * CH + K - 1;     // padded LDS row width
    constexpr int RS = 2 * IPG / PHASES;    // rows staged per phase
    static_assert(NW * KSEL <= RS * W2, "stage region fits in xs");

    const int t = threadIdx.x;
    // XCD-aware remap (bijective: GRIDJ*64 = 8 xcd * (GRIDJ*8))
    const int lin = blockIdx.x + blockIdx.y * GRIDJ;
    const int xcd = lin & 7;
    const int q   = lin >> 3;
    const int j   = q >> 3;                 // 0..GRIDJ-1
    const int b   = (xcd << 3) + (q & 7);   // all j of b on one xcd
    const int wav = t >> 6, lane = t & 63;

    __shared__ __align__(16) float xs[RS][W2];

    const float* Xb = X + ((size_t)b * Cin + (size_t)(2 * j) * IPG) * SIN;

    const int f0 = __builtin_amdgcn_readfirstlane(2 * wav);
    float acc0[CH], acc1[CH];
    {
        float bias0 = Bias[2 * j * NF + f0]     + Bias[(2 * j + 1) * NF + f0];
        float bias1 = Bias[2 * j * NF + f0 + 1] + Bias[(2 * j + 1) * NF + f0 + 1];
        #pragma unroll
        for (int i = 0; i < CH; ++i) { acc0[i] = bias0; acc1[i] = bias1; }
    }
    const int base = lane * CH;

    #pragma unroll 1
    for (int ph = 0; ph < PHASES; ++ph) {
        if (ph) __syncthreads();            // prior phase's reads done
        for (int idx = t; idx < RS * W2; idx += NW * 64) {
            int r = idx / W2, p = idx - r * W2;
            int sg = p - (K - 1);
            int gr = ph * RS + r;
            xs[r][p] = (sg >= 0 && sg < SIN) ? Xb[(size_t)gr * SIN + sg] : 0.f;
        }
        __syncthreads();

        int h = (ph * RS) / IPG, c = (ph * RS) % IPG;
        #pragma unroll 1
        for (int r = 0; r < RS; ++r) {
            float win[CH + K - 1];
            #pragma unroll
            for (int p = 0; p < CH + K - 1; ++p)
                win[p] = xs[r][base + p];
            const float* Wp = W + ((size_t)((2 * j + h) * NF + f0) * IPG + c) * K;
            #pragma unroll
            for (int k2 = 0; k2 < K; ++k2) {
                const float w0 = Wp[k2];
                const float w1 = Wp[(size_t)IPG * K + k2];
                #pragma unroll
                for (int i = 0; i < CH; ++i) {
                    acc0[i] = fmaf(win[i + k2], w0, acc0[i]);
                    acc1[i] = fmaf(win[i + k2], w1, acc1[i]);
                }
            }
            if (++c == IPG) { c = 0; ++h; }
        }
    }

    // xs is dead now (all conv reads done); barrier, then reuse as stage.
    __syncthreads();

    unsigned keys[2][CH];
    #pragma unroll
    for (int i = 0; i < CH; ++i) {
        keys[0][i] = (base + i < SOUT) ? f2ord(acc0[i]) : 0u;
        keys[1][i] = (base + i < SOUT) ? f2ord(acc1[i]) : 0u;
    }
    const size_t orow = (size_t)b * Cfold + (size_t)j * NF;
    float* outs[2] = { Z + (orow + f0) * (size_t)KSEL,
                       Z + (orow + f0 + 1) * (size_t)KSEL };
    float* stage = ((float*)xs) + wav * KSEL;
    wave_selectN_ballot<2, CH>(keys, KSEL, stage, outs);
}

// ---------------------------------------------------------------------------
// FC: (64,352) @ (6,352)^T + b
// ---------------------------------------------------------------------------
__global__ __launch_bounds__(192) void fc_kernel(
    const float* __restrict__ Z, const float* __restrict__ Wf,
    const float* __restrict__ bf, float* __restrict__ out)
{
    int g = blockIdx.x * blockDim.x + threadIdx.x;
    if (g >= 64 * 6) return;
    int b = g / 6, c = g % 6;
    float acc = bf[c];
    const float* zr = Z + b * 352;
    const float* wr = Wf + c * 352;
    for (int i = 0; i < 352; ++i) acc += zr[i] * wr[i];
    out[g] = acc;
}

extern "C" void kernel_launch(void* const* d_in, const int* in_sizes, int n_in,
                              void* d_out, int out_size, void* d_ws, size_t ws_size,
                              hipStream_t stream)
{
    const int*   tokens = (const int*)  d_in[0];
    const float* emb    = (const float*)d_in[1];
    const float* w1     = (const float*)d_in[2];
    const float* b1     = (const float*)d_in[3];
    const float* w2     = (const float*)d_in[4];
    const float* b2     = (const float*)d_in[5];
    const float* w3     = (const float*)d_in[6];
    const float* b3     = (const float*)d_in[7];
    const float* w4     = (const float*)d_in[8];
    const float* b4     = (const float*)d_in[9];
    const float* fcw    = (const float*)d_in[10];
    const float* fcb    = (const float*)d_in[11];
    float* out = (float*)d_out;
    float* ws  = (float*)d_ws;

    // workspace layout (floats) — Z1 no longer exists (fused away):
    //  Z2 [15728640, 23068672)   64*224*512  (29 MB)
    //  Z3 [0,         2359296)   64*144*256
    //  Z4 [2359296,   2381824)   64*88*4
    float* Z2 = ws + 15728640;
    float* Z3 = ws;
    float* Z4 = ws + 2359296;

    // L1+L2 fused: emb gather + pair conv K=7 + fold + top768 + tanh (LDS)
    //              + grouped conv IPG=10 K=5 + fold + top512 + tanh -> Z2
    layer12_fused<<<dim3(16, 64), 896, 0, stream>>>(
        tokens, emb, w1, b1, w2, b2, Z2);

    // L3: IPG=14 NF=18 K=5  512->516, keep 256.  NW=9, CH=9, 4-phase
    //     (xs 7x580x4 = 16.2KB; stage reuses xs), XCD swizzle GRIDJ=8
    conv_fold_select_kernel<14, 18, 5, 512, 516, 256, 9, 9, 4, 8>
        <<<dim3(8, 64), 9 * 64, 0, stream>>>(Z2, w3, b3, Z3, 224, 144);

    // L4: IPG=18 NF=22 K=3  256->258, keep 4.  NW=11, CH=5, 1-phase,
    //     XCD swizzle GRIDJ=4 (stage reuses xs; LDS 46.4KB)
    conv_fold_select_kernel<18, 22, 3, 256, 258, 4, 11, 5, 1, 4>
        <<<dim3(4, 64), 11 * 64, 0, stream>>>(Z3, w4, b4, Z4, 144, 88);

    fc_kernel<<<2, 192, 0, stream>>>(Z4, fcw, fcb, out);
}

// Round 16
// 309.616 us; speedup vs baseline: 1.3105x; 1.3105x over previous
//
#include <hip/hip_runtime.h>
#include <hip/hip_bf16.h>
#include <math.h>

// ---------------------------------------------------------------------------
// DeepDCNN: emb-gather -> 4x [grouped full-conv + pair-fold + ordered top-k +
// tanh] -> FC.  All fp32.
//
// FINAL = R13 verbatim (309.7us best, absmax 0.0; verified Round 13).
// R15's bench was an infra failure (GPU acquisition timeout) -- resubmitted
// unchanged.
//
// Wins banked: R4 L1+L2 fusion (kills Z1 63MB round trip), R6 layer12 XCD
// swizzle (FETCH 56->8.6MB; emb L2-resident per XCD), R7 L3/L4 XCD swizzle +
// L3 multi-phase staging, R12/R13 dead-buffer stage reuse (stagebufs
// eliminated; selects stage into dead z1/xs behind one barrier).
//
// CLOSED lines (do not revisit): DPP counting (R8 spill), shared-template
// hybrid (R9 spill), launch_bounds(896,7) (R10: hint read as 14 waves/SIMD,
// 36-VGPR alloc), LDS-histogram radix (R11: exponent-byte bucket skew ->
// 14.7M bank-conflict cyc + absmax drift), layer12-only hybrid + deferred
// bias (R14 spill), LDS-residency shrinks (R12/R13 nulls), pipe-shuffles
// (R2/R3 neutral on clean totals).
// Model: clean total tracks TOTAL issued work + HBM traffic (power/clock-
// capped); profiled per-kernel gains that don't remove work don't translate.
// ---------------------------------------------------------------------------

#if defined(__has_builtin)
#if __has_builtin(__builtin_amdgcn_ballot_w64)
#define BALLOT64(expr) __builtin_amdgcn_ballot_w64(expr)
#endif
#endif
#ifndef BALLOT64
#define BALLOT64(expr) __ballot(expr)
#endif

__device__ __forceinline__ unsigned f2ord(float f) {
    unsigned u = __float_as_uint(f);
    return (u & 0x80000000u) ? ~u : (u | 0x80000000u);
}
__device__ __forceinline__ float ord2f(unsigned key) {
    unsigned u = (key & 0x80000000u) ? (key & 0x7fffffffu) : ~key;
    return __uint_as_float(u);
}
// tanh via exp + hw rcp: 1 - 2*rcp(e^{2x}+1).  |err| ~1e-7.  Keys are
// pre-tanh so selection ordering is unaffected.
__device__ __forceinline__ float tanh_fast(float x) {
    float e = __expf(2.f * x);
    return 1.f - 2.f * __builtin_amdgcn_rcpf(e + 1.f);
}
__device__ __forceinline__ int mbcnt64(unsigned long long m) {
    return __builtin_amdgcn_mbcnt_hi((unsigned)(m >> 32),
           __builtin_amdgcn_mbcnt_lo((unsigned)m, 0u));
}

// ---- compaction + tanh -> stage (LDS) [-> optional coalesced copy-out] ----
// T = threshold key; stable (earliest ties kept), order-preserving.
// COPY=false: kept values land scattered-compacted in stage and stay there
// (used by the fused kernel, stage = conv-input row in LDS).
// COPY=true: float4 copy stage -> out (k multiple of 4; 16B-aligned rows).
template<int CH, bool COPY>
__device__ __forceinline__ void select_finish(const unsigned* keys, unsigned T,
                                              int k, float* stage,
                                              float* __restrict__ out)
{
    int g = 0, e = 0;
    #pragma unroll
    for (int i = 0; i < CH; ++i) { g += (keys[i] > T); e += (keys[i] == T); }

    int gtBefore = 0, eqBefore = 0, totG = 0;
    #pragma unroll
    for (int b = 0; b < 5; ++b) {     // CH <= 17 < 32 -> 5 bits
        unsigned long long mg = BALLOT64((((g >> b) & 1) != 0));
        unsigned long long me = BALLOT64((((e >> b) & 1) != 0));
        gtBefore += mbcnt64(mg) << b;
        eqBefore += mbcnt64(me) << b;
        totG     += __popcll(mg) << b;
    }
    const int needTies = k - totG;    // # of ==T to keep (earliest)

    int gRun = 0, eRun = 0;
    #pragma unroll
    for (int i = 0; i < CH; ++i) {
        const unsigned key = keys[i];
        const bool isG = key > T;
        const bool isE = key == T;
        const int eIdx = eqBefore + eRun;
        const int dst = gtBefore + gRun + min(eIdx, needTies);
        if (isG || (isE && eIdx < needTies))
            stage[dst] = tanh_fast(ord2f(key));
        gRun += isG; eRun += isE;
    }
    if (COPY) {
        // coalesced vectorized copy-out (same-wave DS ordering makes the
        // scatter-write -> contiguous-read sequence safe without barriers)
        const int lane = threadIdx.x & 63;
        const float4* s4 = (const float4*)stage;
        float4* o4 = (float4*)out;
        #pragma unroll 1
        for (int i = lane; i < (k >> 2); i += 64)
            o4[i] = s4[i];
    }
}

// ---- single-row exact top-k (one chain per wave), ballot counting --------
// Lane holds contiguous chunk [lane*CH, ...) of the row as order-keys in
// regs; invalid slots MUST be 0 (all finite-float keys are >= 0x00800000).
template<int CH, bool COPY>
__device__ void wave_select1(const unsigned* keys, int k, float* stage,
                             float* __restrict__ out)
{
    unsigned p = 0u;
    int above = 0, buck = 64 * CH;
    #pragma unroll 1
    for (int pos = 31; pos >= 0; --pos) {
        const unsigned t = p | (1u << pos);
        int c = 0;
        #pragma unroll
        for (int i = 0; i < CH; ++i)
            c += __popcll(BALLOT64((keys[i] >= t)));
        const int inb = c - above;        // bucket members with bit=1
        const int rem = k - above;
        if (inb >= rem) { p = t; buck = inb; }
        else            { above += inb; buck -= inb; }
        if (buck == k - above) break;
    }
    select_finish<CH, COPY>(keys, p, k, stage, out);
}

// ---- N-row exact top-k, interleaved chains (conv L3/L4, N=2) -------------
template<int N, int CH>
__device__ void wave_selectN_ballot(const unsigned (*keys)[CH], int k,
                                    float* stage, float* const* outs)
{
    unsigned p[N];
    int above[N], buck[N];
    #pragma unroll
    for (int n = 0; n < N; ++n) { p[n] = 0u; above[n] = 0; buck[n] = 64 * CH; }

    unsigned doneMask = 0;
    const unsigned allDone = (1u << N) - 1u;
    #pragma unroll 1
    for (int pos = 31; pos >= 0; --pos) {
        #pragma unroll
        for (int n = 0; n < N; ++n) {
            if (!((doneMask >> n) & 1u)) {        // wave-uniform branch
                const unsigned t = p[n] | (1u << pos);
                int c = 0;
                #pragma unroll
                for (int i = 0; i < CH; ++i)
                    c += __popcll(BALLOT64((keys[n][i] >= t)));
                const int inb = c - above[n];
                const int rem = k - above[n];
                if (inb >= rem) { p[n] = t; buck[n] = inb; }
                else            { above[n] += inb; buck[n] -= inb; }
                if (buck[n] == k - above[n]) doneMask |= (1u << n);
            }
        }
        if (doneMask == allDone) break;
    }
    #pragma unroll
    for (int n = 0; n < N; ++n)
        select_finish<CH, true>(keys[n], p[n], k, stage, outs[n]);
}

// ---------------------------------------------------------------------------
// Fused layers 1+2.  grid (16, 64) -> XCD-swizzled to (j2, b), block 896 =
// 14 waves.
// Per block:
//   phase ph=0/1 (L1 group g = 2*j2+ph):
//     - waves 0..9: L1 conv row f1=wav (emb dims 2g,2g+1 from LDS xr),
//       exact top-768 select + tanh written DIRECTLY into z1[wav][4..772)
//     - all 14 waves: L2 partial conv, filter f=wav, input half h=ph
//     - xr restage for ph=1 overlaps the ph=0 accumulation
//   epilogue: barrier (z1 dead), top-512 select per filter staged into z1
//   -> float4 write to Z2.
// LDS: z1 10x836x4 = 33.4 KB + uni(xr[2][1100]) 8.8 KB = 41.3 KB.
// XCD swizzle: all 16 j2-blocks of batch b land on xcd = b>>3.  Per-XCD emb
// working set 8 b x 1024 tok x 256 B = 2 MB < 4 MB L2 (R6: FETCH 56->8.6MB).
// ---------------------------------------------------------------------------
__global__ __launch_bounds__(896) void layer12_fused(
    const int* __restrict__ tokens, const float* __restrict__ emb,
    const float* __restrict__ W1, const float* __restrict__ B1,
    const float* __restrict__ W2, const float* __restrict__ B2,
    float* __restrict__ Z2)
{
    // XCD-aware remap (bijective: 1024 = 8 xcd * 128)
    const int lin = blockIdx.x + (blockIdx.y << 4);
    const int xcd = lin & 7;
    const int q   = lin >> 3;           // 0..127
    const int j2  = q >> 3;             // 0..15
    const int b   = (xcd << 3) + (q & 7); // 0..63; all j2 of b on one xcd

    const int t  = threadIdx.x;
    const int wav  = t >> 6;            // 0..13
    const int lane = t & 63;

    __shared__ __align__(16) float z1[10][836];
    __shared__ __align__(16) float uni[2 * 1100];   // xr[2][1100]
    float (*xr)[1100] = reinterpret_cast<float (*)[1100]>(uni);
    const float2* emb2 = (const float2*)emb;

    // zero ONLY the pad words: [0,4) and [772,836) per row (68 words x 10
    // rows).  The value region [4,772) is fully overwritten by each phase's
    // select before any read.
    for (int i = t; i < 680; i += 896) {
        const int r = i / 68;
        const int w = i - r * 68;
        z1[r][(w < 4) ? w : (768 + w)] = 0.f;
    }

    // L2 accumulator: filter f = wav, bias = folded pair of halves
    const int f = __builtin_amdgcn_readfirstlane(wav);
    float acc[13];
    {
        const float bias = B2[(2 * j2) * 14 + f] + B2[(2 * j2 + 1) * 14 + f];
        #pragma unroll
        for (int i = 0; i < 13; ++i) acc[i] = bias;
    }
    const int base = lane * 13;

    // stage xr for phase 0 (L1 group g = 2*j2; emb dim pair g)
    {
        const int g = 2 * j2;
        for (int i = t; i < 1100; i += 896) {
            int s = i - 6; float a = 0.f, c = 0.f;
            if (s >= 0 && s < 1024) {
                int tok = tokens[b * 1024 + s];
                float2 v = emb2[(size_t)tok * 32 + g];
                a = v.x; c = v.y;
            }
            xr[0][i] = a; xr[1][i] = c;
        }
    }
    __syncthreads();   // xr(0) + z1 pad zeros visible

    #pragma unroll 1
    for (int ph = 0; ph < 2; ++ph) {
        const int g = 2 * j2 + ph;

        // ---- L1: conv + select + tanh -> z1 row (waves 0..9) ----
        if (wav < 10) {
            const int f1 = wav;
            float wa[7], wb[7];
            #pragma unroll
            for (int k2 = 0; k2 < 7; ++k2) {
                wa[k2] = W1[(2 * g * 10 + f1) * 7 + k2];
                wb[k2] = W1[((2 * g + 1) * 10 + f1) * 7 + k2];
            }
            const float bias1 = B1[2 * g * 10 + f1] + B1[(2 * g + 1) * 10 + f1];
            const int beg = lane * 17;
            unsigned keys1[17];
            #pragma unroll
            for (int i = 0; i < 17; ++i) {
                float a1 = bias1;
                #pragma unroll
                for (int k2 = 0; k2 < 7; ++k2)
                    a1 += xr[0][beg + i + k2] * wa[k2]
                        + xr[1][beg + i + k2] * wb[k2];
                keys1[i] = (beg + i < 1030) ? f2ord(a1) : 0u;
            }
            wave_select1<17, false>(keys1, 768, &z1[wav][4], nullptr);
        }
        __syncthreads();   // z1(ph) ready; all xr reads of this phase done

        if (ph == 0) {
            // restage xr for phase 1 — overlaps the h=0 accumulation below
            const int g1 = 2 * j2 + 1;
            for (int i = t; i < 1100; i += 896) {
                int s = i - 6; float a = 0.f, c = 0.f;
                if (s >= 0 && s < 1024) {
                    int tok = tokens[b * 1024 + s];
                    float2 v = emb2[(size_t)tok * 32 + g1];
                    a = v.x; c = v.y;
                }
                xr[0][i] = a; xr[1][i] = c;
            }
        }

        // ---- L2 partial conv: all 14 waves, filter f, half h=ph ----
        {
            const float* Wp0 = W2 + (size_t)((2 * j2 + ph) * 14 + f) * 10 * 5;
            #pragma unroll 1
            for (int r = 0; r < 10; ++r) {
                float win[17];
                #pragma unroll
                for (int p = 0; p < 17; ++p) win[p] = z1[r][base + p];
                const float* Wp = Wp0 + r * 5;
                #pragma unroll
                for (int k2 = 0; k2 < 5; ++k2) {
                    const float w0 = Wp[k2];
                    #pragma unroll
                    for (int i = 0; i < 13; ++i)
                        acc[i] = fmaf(win[i + k2], w0, acc[i]);
                }
            }
        }
        if (ph == 0) __syncthreads();  // xr(1) staged & z1(0) fully consumed
    }

    // ---- L2 select: one chain per wave, k=512, staged into DEAD z1 ----
    // Barrier: every wave must finish its h=1 conv reads of z1 before any
    // wave overwrites z1 with its stage data.
    __syncthreads();
    unsigned keys2[13];
    #pragma unroll
    for (int i = 0; i < 13; ++i)
        keys2[i] = (base + i < 772) ? f2ord(acc[i]) : 0u;
    float* stage = ((float*)z1) + wav * 512;   // 14*512 = 7168 <= 8360 words
    float* outp = Z2 + ((size_t)b * 224 + (size_t)j2 * 14 + f) * 512;
    wave_select1<13, true>(keys2, 512, stage, outp);
}

// ---------------------------------------------------------------------------
// Fused conv + fold + select + tanh (layers 3-4).
// grid (GRIDJ j, 64 b) -> XCD-swizzled so all j-blocks of batch b land on
// xcd = b>>3 (matches layer12's Z2/Z3 placement -> producer-L2 hits).
// Wave w computes output rows (filters) f = 2w, 2w+1 (length SOUT), then
// dual-chain selects top-KSEL of each, staged into xs (DEAD after the conv;
// barrier before reuse).  No dedicated stagebuf -> L3 LDS 41.7 -> 16.3KB.
// ---------------------------------------------------------------------------
template <int IPG, int NF, int K, int SIN, int SOUT, int KSEL, int NW, int CH,
          int PHASES, int GRIDJ>
__global__ __launch_bounds__(NW * 64) void conv_fold_select_kernel(
    const float* __restrict__ X, const float* __restrict__ W,
    const float* __restrict__ Bias, float* __restrict__ Z,
    int Cin, int Cfold)
{
    static_assert(NF == 2 * NW, "2 filters per wave");
    static_assert(64 * CH >= SOUT, "chunk covers row");
    constexpr int W2 = 64 * CH + K - 1;     // padded LDS row width
    constexpr int RS = 2 * IPG / PHASES;    // rows staged per phase
    static_assert(NW * KSEL <= RS * W2, "stage region fits in xs");

    const int t = threadIdx.x;
    // XCD-aware remap (bijective: GRIDJ*64 = 8 xcd * (GRIDJ*8))
    const int lin = blockIdx.x + blockIdx.y * GRIDJ;
    const int xcd = lin & 7;
    const int q   = lin >> 3;
    const int j   = q >> 3;                 // 0..GRIDJ-1
    const int b   = (xcd << 3) + (q & 7);   // all j of b on one xcd
    const int wav = t >> 6, lane = t & 63;

    __shared__ __align__(16) float xs[RS][W2];

    const float* Xb = X + ((size_t)b * Cin + (size_t)(2 * j) * IPG) * SIN;

    const int f0 = __builtin_amdgcn_readfirstlane(2 * wav);
    float acc0[CH], acc1[CH];
    {
        float bias0 = Bias[2 * j * NF + f0]     + Bias[(2 * j + 1) * NF + f0];
        float bias1 = Bias[2 * j * NF + f0 + 1] + Bias[(2 * j + 1) * NF + f0 + 1];
        #pragma unroll
        for (int i = 0; i < CH; ++i) { acc0[i] = bias0; acc1[i] = bias1; }
    }
    const int base = lane * CH;

    #pragma unroll 1
    for (int ph = 0; ph < PHASES; ++ph) {
        if (ph) __syncthreads();            // prior phase's reads done
        for (int idx = t; idx < RS * W2; idx += NW * 64) {
            int r = idx / W2, p = idx - r * W2;
            int sg = p - (K - 1);
            int gr = ph * RS + r;
            xs[r][p] = (sg >= 0 && sg < SIN) ? Xb[(size_t)gr * SIN + sg] : 0.f;
        }
        __syncthreads();

        int h = (ph * RS) / IPG, c = (ph * RS) % IPG;
        #pragma unroll 1
        for (int r = 0; r < RS; ++r) {
            float win[CH + K - 1];
            #pragma unroll
            for (int p = 0; p < CH + K - 1; ++p)
                win[p] = xs[r][base + p];
            const float* Wp = W + ((size_t)((2 * j + h) * NF + f0) * IPG + c) * K;
            #pragma unroll
            for (int k2 = 0; k2 < K; ++k2) {
                const float w0 = Wp[k2];
                const float w1 = Wp[(size_t)IPG * K + k2];
                #pragma unroll
                for (int i = 0; i < CH; ++i) {
                    acc0[i] = fmaf(win[i + k2], w0, acc0[i]);
                    acc1[i] = fmaf(win[i + k2], w1, acc1[i]);
                }
            }
            if (++c == IPG) { c = 0; ++h; }
        }
    }

    // xs is dead now (all conv reads done); barrier, then reuse as stage.
    __syncthreads();

    unsigned keys[2][CH];
    #pragma unroll
    for (int i = 0; i < CH; ++i) {
        keys[0][i] = (base + i < SOUT) ? f2ord(acc0[i]) : 0u;
        keys[1][i] = (base + i < SOUT) ? f2ord(acc1[i]) : 0u;
    }
    const size_t orow = (size_t)b * Cfold + (size_t)j * NF;
    float* outs[2] = { Z + (orow + f0) * (size_t)KSEL,
                       Z + (orow + f0 + 1) * (size_t)KSEL };
    float* stage = ((float*)xs) + wav * KSEL;
    wave_selectN_ballot<2, CH>(keys, KSEL, stage, outs);
}

// ---------------------------------------------------------------------------
// FC: (64,352) @ (6,352)^T + b
// ---------------------------------------------------------------------------
__global__ __launch_bounds__(192) void fc_kernel(
    const float* __restrict__ Z, const float* __restrict__ Wf,
    const float* __restrict__ bf, float* __restrict__ out)
{
    int g = blockIdx.x * blockDim.x + threadIdx.x;
    if (g >= 64 * 6) return;
    int b = g / 6, c = g % 6;
    float acc = bf[c];
    const float* zr = Z + b * 352;
    const float* wr = Wf + c * 352;
    for (int i = 0; i < 352; ++i) acc += zr[i] * wr[i];
    out[g] = acc;
}

extern "C" void kernel_launch(void* const* d_in, const int* in_sizes, int n_in,
                              void* d_out, int out_size, void* d_ws, size_t ws_size,
                              hipStream_t stream)
{
    const int*   tokens = (const int*)  d_in[0];
    const float* emb    = (const float*)d_in[1];
    const float* w1     = (const float*)d_in[2];
    const float* b1     = (const float*)d_in[3];
    const float* w2     = (const float*)d_in[4];
    const float* b2     = (const float*)d_in[5];
    const float* w3     = (const float*)d_in[6];
    const float* b3     = (const float*)d_in[7];
    const float* w4     = (const float*)d_in[8];
    const float* b4     = (const float*)d_in[9];
    const float* fcw    = (const float*)d_in[10];
    const float* fcb    = (const float*)d_in[11];
    float* out = (float*)d_out;
    float* ws  = (float*)d_ws;

    // workspace layout (floats) — Z1 no longer exists (fused away):
    //  Z2 [15728640, 23068672)   64*224*512  (29 MB)
    //  Z3 [0,         2359296)   64*144*256
    //  Z4 [2359296,   2381824)   64*88*4
    float* Z2 = ws + 15728640;
    float* Z3 = ws;
    float* Z4 = ws + 2359296;

    // L1+L2 fused: emb gather + pair conv K=7 + fold + top768 + tanh (LDS)
    //              + grouped conv IPG=10 K=5 + fold + top512 + tanh -> Z2
    layer12_fused<<<dim3(16, 64), 896, 0, stream>>>(
        tokens, emb, w1, b1, w2, b2, Z2);

    // L3: IPG=14 NF=18 K=5  512->516, keep 256.  NW=9, CH=9, 4-phase
    //     (xs 7x580x4 = 16.2KB; stage reuses xs), XCD swizzle GRIDJ=8
    conv_fold_select_kernel<14, 18, 5, 512, 516, 256, 9, 9, 4, 8>
        <<<dim3(8, 64), 9 * 64, 0, stream>>>(Z2, w3, b3, Z3, 224, 144);

    // L4: IPG=18 NF=22 K=3  256->258, keep 4.  NW=11, CH=5, 1-phase,
    //     XCD swizzle GRIDJ=4 (stage reuses xs; LDS 46.4KB)
    conv_fold_select_kernel<18, 22, 3, 256, 258, 4, 11, 5, 1, 4>
        <<<dim3(4, 64), 11 * 64, 0, stream>>>(Z3, w4, b4, Z4, 144, 88);

    fc_kernel<<<2, 192, 0, stream>>>(Z4, fcw, fcb, out);
}